// Round 8
// baseline (363.935 us; speedup 1.0000x reference)
//
#include <hip/hip_runtime.h>
#include <hip/hip_bf16.h>

// Problem constants: B=16, N=1024, C=768, H=12, D=64, P=1, L=32 (rope tokens [1,992))
typedef __attribute__((ext_vector_type(8))) short v8s;
typedef __attribute__((ext_vector_type(4))) short v4s;
typedef __attribute__((ext_vector_type(4))) float f32x4;

__device__ __forceinline__ float bf2f(short s){
  unsigned u = ((unsigned)(unsigned short)s) << 16;
  float f; __builtin_memcpy(&f, &u, 4); return f;
}
__device__ __forceinline__ short f2bf(float f){
  unsigned u; __builtin_memcpy(&u, &f, 4);
  unsigned r = (u + 0x7FFFu + ((u >> 16) & 1u)) >> 16;
  return (short)r;
}
// packed RNE f32x2 -> bf16x2 (low = a, high = b); no builtin on gfx950 (m240)
__device__ __forceinline__ unsigned cvtpk(float a, float b){
  unsigned r;
  asm("v_cvt_pk_bf16_f32 %0, %1, %2" : "=v"(r) : "v"(a), "v"(b));
  return r;
}

// async global->LDS DMA, 16B per lane; LDS dest = wave-uniform base + lane*16 (m104)
__device__ __forceinline__ void gload16(const void* g, void* l){
  __builtin_amdgcn_global_load_lds((const __attribute__((address_space(1))) void*)g,
                                   (__attribute__((address_space(3))) void*)l, 16, 0, 0);
}

// ---------------- cast fp32 -> bf16 (8 elems/thread) ----------------
__global__ __launch_bounds__(256) void k_cast8(const float* __restrict__ in,
                                               short* __restrict__ out, long n){
  long i = ((long)blockIdx.x * 256 + threadIdx.x) * 8;
  long stride = (long)gridDim.x * 256 * 8;
  for (; i < n; i += stride){
    float4 a = *(const float4*)(in + i);
    float4 b = *(const float4*)(in + i + 4);
    v8s v;
    v[0]=f2bf(a.x); v[1]=f2bf(a.y); v[2]=f2bf(a.z); v[3]=f2bf(a.w);
    v[4]=f2bf(b.x); v[5]=f2bf(b.y); v[6]=f2bf(b.z); v[7]=f2bf(b.w);
    *(v8s*)(out + i) = v;
  }
}

// ------------- transpose+cast: in[R][Cc] f32 -> out[Cc][R] bf16 -------------
__global__ __launch_bounds__(256) void k_tcast(const float* __restrict__ in,
                                               short* __restrict__ out, int R, int Cc){
  __shared__ float T[32][33];
  int tx = threadIdx.x & 31, ty = threadIdx.x >> 5;
  int r0 = blockIdx.x * 32, c0 = blockIdx.y * 32;
  #pragma unroll
  for (int p = 0; p < 4; p++){
    int r = ty + p*8;
    T[r][tx] = in[(long)(r0 + r)*Cc + c0 + tx];
  }
  __syncthreads();
  #pragma unroll
  for (int p = 0; p < 4; p++){
    int r = ty + p*8;
    out[(long)(c0 + r)*R + r0 + tx] = f2bf(T[tx][r]);
  }
}

// ---------------- bf16 GEMM: C[M][N] = A[M][K]*B[K][N], Bt is [N][K] ----------------
// BM=BN=128 BK=64, 256 threads (4 waves). global_load_lds staging into linear LDS
// with involutive swizzle (colbyte ^= (row&7)<<4) applied to SOURCE addr and READ addr.
template<int OUT_MODE>  // 0: bf16 out, 1: f32 out + bias
__global__ __launch_bounds__(256) void k_gemm(const short* __restrict__ A,
                                              const short* __restrict__ Bt,
                                              void* __restrict__ Cout,
                                              const float* __restrict__ bias,
                                              int M, int N, int K){
  __shared__ short As[128*64];
  __shared__ short Bs[128*64];
  int row0 = blockIdx.x * 128, col0 = blockIdx.y * 128;
  int t = threadIdx.x;
  int lane = t & 63, w = t >> 6;
  int g = lane >> 4, r16 = lane & 15;
  int wr = w >> 1, wc = w & 1;
  int rsw = (r16 & 7) << 3;             // read-side swizzle (shorts)
  int srow = t >> 3;                    // staging row within 32-row shot
  int scol = ((t & 7) * 8) ^ ((srow & 7) << 3);  // pre-swizzled source col (shorts)
  f32x4 acc[4][4];
  #pragma unroll
  for (int mi = 0; mi < 4; mi++)
    #pragma unroll
    for (int ni = 0; ni < 4; ni++)
      acc[mi][ni] = (f32x4){0.f,0.f,0.f,0.f};

  for (int kt = 0; kt < K; kt += 64){
    #pragma unroll
    for (int p = 0; p < 4; p++){
      int rr = p*32 + srow;
      gload16(&A[(long)(row0 + rr)*K + kt + scol], &As[(p*256 + w*64)*8]);
    }
    #pragma unroll
    for (int p = 0; p < 4; p++){
      int rr = p*32 + srow;
      gload16(&Bt[(long)(col0 + rr)*K + kt + scol], &Bs[(p*256 + w*64)*8]);
    }
    __syncthreads();
    #pragma unroll
    for (int ks = 0; ks < 2; ks++){
      v8s af[4], bfr[4];
      #pragma unroll
      for (int mi = 0; mi < 4; mi++)
        af[mi] = *(const v8s*)&As[(wr*64 + mi*16 + r16)*64 + ((ks*32 + g*8) ^ rsw)];
      #pragma unroll
      for (int ni = 0; ni < 4; ni++)
        bfr[ni] = *(const v8s*)&Bs[(wc*64 + ni*16 + r16)*64 + ((ks*32 + g*8) ^ rsw)];
      __builtin_amdgcn_s_setprio(1);
      #pragma unroll
      for (int mi = 0; mi < 4; mi++)
        #pragma unroll
        for (int ni = 0; ni < 4; ni++)
          acc[mi][ni] = __builtin_amdgcn_mfma_f32_16x16x32_bf16(af[mi], bfr[ni], acc[mi][ni], 0, 0, 0);
      __builtin_amdgcn_s_setprio(0);
    }
    __syncthreads();
  }
  #pragma unroll
  for (int mi = 0; mi < 4; mi++)
    #pragma unroll
    for (int ni = 0; ni < 4; ni++){
      int rbase = row0 + wr*64 + mi*16 + g*4;
      int cc = col0 + wc*64 + ni*16 + r16;
      #pragma unroll
      for (int j = 0; j < 4; j++){
        float v = acc[mi][ni][j];
        if (OUT_MODE == 0)
          ((short*)Cout)[(long)(rbase + j)*N + cc] = f2bf(v);
        else
          ((float*)Cout)[(long)(rbase + j)*N + cc] = v + bias[cc];
      }
    }
}

// ---------------- LN (over D=64) + RoPE + layout: QKV bf16 -> Qb, Kb (b,h,n,d), Vt (b,h,d,n) ----------------
// Q additionally scaled by D^-0.5 * log2(e) so attention can use exp2 directly.
__global__ __launch_bounds__(256) void k_lnrope(const short* __restrict__ QKV,
     const float* __restrict__ cosT, const float* __restrict__ sinT,
     const float* __restrict__ qw, const float* __restrict__ qb,
     const float* __restrict__ kw, const float* __restrict__ kb,
     short* __restrict__ Qb, short* __restrict__ Kb, short* __restrict__ Vt){
  __shared__ short Vs[64][72];
  int blk = blockIdx.x;
  int ntile = blk & 15, h = (blk >> 4) % 12, b = blk / 192;
  int t = threadIdx.x;
  int tl = t >> 2, ch = t & 3;
  int n = ntile*64 + tl;
  long row = (long)(b*1024 + n) * 2304;
  int d0 = ch * 16;
  long outrow = ((long)(b*12 + h)*1024 + n) * 64;

  #pragma unroll
  for (int sel = 0; sel < 2; sel++){
    const short* src = &QKV[row + sel*768 + h*64 + d0];
    float f[16];
    v8s a0 = *(const v8s*)src;
    v8s a1 = *(const v8s*)(src + 8);
    #pragma unroll
    for (int i = 0; i < 8; i++){ f[i] = bf2f(a0[i]); f[8+i] = bf2f(a1[i]); }
    float s1 = 0.f, s2 = 0.f;
    #pragma unroll
    for (int i = 0; i < 16; i++){ s1 += f[i]; s2 += f[i]*f[i]; }
    s1 += __shfl_xor(s1, 1); s2 += __shfl_xor(s2, 1);
    s1 += __shfl_xor(s1, 2); s2 += __shfl_xor(s2, 2);
    float mu = s1 * (1.0f/64.0f);
    float var = s2 * (1.0f/64.0f) - mu*mu;
    float rs = rsqrtf(var + 1e-5f);
    const float* wp = sel ? kw : qw;
    const float* bp = sel ? kb : qb;
    #pragma unroll
    for (int i = 0; i < 16; i++) f[i] = (f[i] - mu)*rs*wp[d0+i] + bp[d0+i];
    if (n >= 1 && n < 992){
      int pos = n - 1;
      const float* cp = &cosT[pos*32 + ch*8];
      const float* sp = &sinT[pos*32 + ch*8];
      #pragma unroll
      for (int i = 0; i < 8; i++){
        float c = cp[i], s = sp[i];
        float tr = f[2*i], ti = f[2*i+1];
        f[2*i]   = tr*c - ti*s;
        f[2*i+1] = tr*s + ti*c;
      }
    }
    if (sel == 0){
      #pragma unroll
      for (int i = 0; i < 16; i++) f[i] *= 0.18033688011112042f;  // D^-0.5 * log2(e)
    }
    v8s o0, o1;
    #pragma unroll
    for (int i = 0; i < 8; i++){ o0[i] = f2bf(f[i]); o1[i] = f2bf(f[8+i]); }
    short* dst = sel ? &Kb[outrow + d0] : &Qb[outrow + d0];
    *(v8s*)dst = o0;
    *(v8s*)(dst + 8) = o1;
  }
  // V: copy + transpose via LDS
  {
    const short* vsrc = &QKV[row + 1536 + h*64 + d0];
    *(v8s*)&Vs[tl][d0]     = *(const v8s*)vsrc;
    *(v8s*)&Vs[tl][d0 + 8] = *(const v8s*)(vsrc + 8);
  }
  __syncthreads();
  {
    int d = tl, nch = ch;
    v8s o0, o1;
    #pragma unroll
    for (int i = 0; i < 8; i++){ o0[i] = Vs[nch*16 + i][d]; o1[i] = Vs[nch*16 + 8 + i][d]; }
    long vrow = ((long)(b*12 + h)*64 + d)*1024 + ntile*64 + nch*16;
    *(v8s*)&Vt[vrow]     = o0;
    *(v8s*)&Vt[vrow + 8] = o1;
  }
}

// ---------------- flash attention: block = (b,h,qtile=128), 512 threads (8 waves) ----------------
// Wave owns 16 q rows. S^T = K*Q^T so sacc C-regs hold P for q=r16, k=16f+4g+j.
// PV: full-K32 MFMAs, key permutation pi shared by A (cvt_pk'd P, lane-local) and B (Vts reads).
// NEW: double-buffered K/V staging with counted overlap (issue t+1 before compute of t,
// single vmcnt(0)+s_barrier per tile at the END) + defer-max (T13, log2-domain THR=8).
__global__ __launch_bounds__(512) void k_attn(const short* __restrict__ Qb,
                                              const short* __restrict__ Kb,
                                              const short* __restrict__ Vt,
                                              short* __restrict__ O){
  __shared__ short Ks[2][64*64];
  __shared__ short Vts[2][64*64];
  int blk = blockIdx.x;
  int qt = blk & 7, h = (blk >> 3) % 12, b = blk / 96;
  long bh = b*12 + h;
  int t = threadIdx.x, lane = t & 63, w = t >> 6;
  int g = lane >> 4, r16 = lane & 15;
  int rsw = (r16 & 7) << 3;
  int q0 = qt*128 + w*16;

  // staging: 512 threads x 16B = 8KB = one 64x64 bf16 tile per shot
  int srow = t >> 3;                                // 0..63
  int scol = ((t & 7) * 8) ^ ((srow & 7) << 3);     // pre-swizzled col (shorts)
  const short* Ksrc = &Kb[(bh*1024 + srow)*64 + scol];
  const short* Vsrc = &Vt[(bh*64 + srow)*1024 + scol];
  int lbase = w*512;                                // wave-uniform LDS dest (shorts)

  // prologue: stage tile 0 into buffer 0
  gload16(Ksrc, &Ks[0][lbase]);
  gload16(Vsrc, &Vts[0][lbase]);

  v8s bq[2];
  #pragma unroll
  for (int tt = 0; tt < 2; tt++)
    bq[tt] = *(const v8s*)&Qb[(bh*1024 + q0 + r16)*64 + tt*32 + g*8];

  f32x4 oacc[4];
  #pragma unroll
  for (int t2 = 0; t2 < 4; t2++) oacc[t2] = (f32x4){0.f,0.f,0.f,0.f};
  float m_run = -1e30f, l_run = 0.f;

  asm volatile("s_waitcnt vmcnt(0)" ::: "memory");
  __builtin_amdgcn_s_barrier();
  asm volatile("" ::: "memory");

  for (int it = 0; it < 16; ++it){
    int cur = it & 1;
    if (it < 15){  // issue next tile's loads early; they overlap this tile's compute
      int kt = (it + 1) * 64;
      gload16(Ksrc + (long)kt*64, &Ks[cur^1][lbase]);
      gload16(Vsrc + kt,          &Vts[cur^1][lbase]);
    }
    const short* KsC  = &Ks[cur][0];
    const short* VtsC = &Vts[cur][0];

    f32x4 sacc[4];
    #pragma unroll
    for (int f = 0; f < 4; f++) sacc[f] = (f32x4){0.f,0.f,0.f,0.f};
    #pragma unroll
    for (int tt = 0; tt < 2; tt++){
      v8s ak[4];
      #pragma unroll
      for (int f = 0; f < 4; f++)
        ak[f] = *(const v8s*)&KsC[(f*16 + r16)*64 + ((tt*32 + g*8) ^ rsw)];
      __builtin_amdgcn_s_setprio(1);
      #pragma unroll
      for (int f = 0; f < 4; f++)
        sacc[f] = __builtin_amdgcn_mfma_f32_16x16x32_bf16(ak[f], bq[tt], sacc[f], 0, 0, 0);
      __builtin_amdgcn_s_setprio(0);
    }
    // tile max (tree) ; lane holds q = r16; k = kt + 16f + 4g + j
    float mf[4];
    #pragma unroll
    for (int f = 0; f < 4; f++)
      mf[f] = fmaxf(fmaxf(sacc[f][0], sacc[f][1]), fmaxf(sacc[f][2], sacc[f][3]));
    float mt = fmaxf(fmaxf(mf[0], mf[1]), fmaxf(mf[2], mf[3]));
    mt = fmaxf(mt, __shfl_xor(mt, 16));
    mt = fmaxf(mt, __shfl_xor(mt, 32));
    // defer-max (T13): only rescale when the running max grew by > 8 (log2 domain, P <= 2^8)
    if (!__all(mt - m_run <= 8.0f)){
      float m_new = fmaxf(m_run, mt);
      float alpha = exp2f(m_run - m_new);
      float aj4[4];
      #pragma unroll
      for (int j = 0; j < 4; j++) aj4[j] = __shfl(alpha, 4*g + j, 64);
      #pragma unroll
      for (int t2 = 0; t2 < 4; t2++)
        #pragma unroll
        for (int j = 0; j < 4; j++) oacc[t2][j] *= aj4[j];
      l_run *= alpha;
      m_run = m_new;
    }
    float p[4][4];
    float ls[4];
    #pragma unroll
    for (int f = 0; f < 4; f++){
      #pragma unroll
      for (int j = 0; j < 4; j++) p[f][j] = exp2f(sacc[f][j] - m_run);
      ls[f] = (p[f][0] + p[f][1]) + (p[f][2] + p[f][3]);
    }
    float lsum = (ls[0] + ls[1]) + (ls[2] + ls[3]);
    lsum += __shfl_xor(lsum, 16);
    lsum += __shfl_xor(lsum, 32);
    l_run += lsum;

    // pack P to bf16: D[f] = (pk(p0,p1), pk(p2,p3)); A-frag W[kb] = D[2kb]||D[2kb+1]
    unsigned d00 = cvtpk(p[0][0], p[0][1]), d01 = cvtpk(p[0][2], p[0][3]);
    unsigned d10 = cvtpk(p[1][0], p[1][1]), d11 = cvtpk(p[1][2], p[1][3]);
    unsigned d20 = cvtpk(p[2][0], p[2][1]), d21 = cvtpk(p[2][2], p[2][3]);
    unsigned d30 = cvtpk(p[3][0], p[3][1]), d31 = cvtpk(p[3][2], p[3][3]);
    union PU { v8s s; unsigned u[4]; };
    PU pa0, pa1;
    pa0.u[0]=d00; pa0.u[1]=d01; pa0.u[2]=d10; pa0.u[3]=d11;
    pa1.u[0]=d20; pa1.u[1]=d21; pa1.u[2]=d30; pa1.u[3]=d31;

    // PV: B-frag lane supplies V[pi(kb,8g+i)][d=t2*16+r16] = two 4-elem runs of Vts row
    #pragma unroll
    for (int t2 = 0; t2 < 4; t2++){
      int vrow = (t2*16 + r16)*64;
      #pragma unroll
      for (int kb = 0; kb < 2; kb++){
        union VU { v8s s; v4s h[2]; } vb;
        vb.h[0] = *(const v4s*)&VtsC[vrow + ((kb*32 + g*4) ^ rsw)];
        vb.h[1] = *(const v4s*)&VtsC[vrow + ((kb*32 + 16 + g*4) ^ rsw)];
        __builtin_amdgcn_s_setprio(1);
        oacc[t2] = __builtin_amdgcn_mfma_f32_16x16x32_bf16(kb ? pa1.s : pa0.s, vb.s, oacc[t2], 0, 0, 0);
        __builtin_amdgcn_s_setprio(0);
      }
    }
    // end-of-tile sync: wait next tile's staged loads, then barrier (buffer swap safe)
    asm volatile("s_waitcnt vmcnt(0)" ::: "memory");
    __builtin_amdgcn_s_barrier();
    asm volatile("" ::: "memory");
  }
  float linv = 1.0f / l_run;
  float lj[4];
  #pragma unroll
  for (int j = 0; j < 4; j++) lj[j] = __shfl(linv, 4*g + j, 64);
  #pragma unroll
  for (int t2 = 0; t2 < 4; t2++)
    #pragma unroll
    for (int j = 0; j < 4; j++){
      float v = oacc[t2][j] * lj[j];
      O[((long)b*1024 + q0 + 4*g + j)*768 + h*64 + t2*16 + r16] = f2bf(v);
    }
}

extern "C" void kernel_launch(void* const* d_in, const int* in_sizes, int n_in,
                              void* d_out, int out_size, void* d_ws, size_t ws_size,
                              hipStream_t stream) {
  const float* x      = (const float*)d_in[0];
  const float* cosT   = (const float*)d_in[1];
  const float* sinT   = (const float*)d_in[2];
  const float* w_qkv  = (const float*)d_in[3];
  const float* q_ln_w = (const float*)d_in[4];
  const float* q_ln_b = (const float*)d_in[5];
  const float* k_ln_w = (const float*)d_in[6];
  const float* k_ln_b = (const float*)d_in[7];
  const float* w_proj = (const float*)d_in[8];
  const float* b_proj = (const float*)d_in[9];

  char* ws = (char*)d_ws;
  short* Xb       = (short*)(ws);                    // 16384x768   bf16: 25165824 B
  short* Wqkv_bt  = (short*)(ws + 25165824);         // 2304x768    bf16:  3538944 B
  short* Wproj_bt = (short*)(ws + 28704768);         // 768x768     bf16:  1179648 B
  short* QKV      = (short*)(ws + 29884416);         // 16384x2304  bf16: 75497472 B
  short* Qb       = (short*)(ws + 105381888);        // (b,h,n,d)   bf16: 25165824 B
  short* Kb       = (short*)(ws + 130547712);        // (b,h,n,d)   bf16: 25165824 B
  short* Vt       = (short*)(ws + 155713536);        // (b,h,d,n)   bf16: 25165824 B
  short* O        = (short*)(ws + 180879360);        // 16384x768   bf16: 25165824 B
  // total 206045184 B

  k_cast8<<<6144, 256, 0, stream>>>(x, Xb, 12582912L);
  k_tcast<<<dim3(24, 72), 256, 0, stream>>>(w_qkv, Wqkv_bt, 768, 2304);
  k_tcast<<<dim3(24, 24), 256, 0, stream>>>(w_proj, Wproj_bt, 768, 768);
  k_gemm<0><<<dim3(128, 18), 256, 0, stream>>>(Xb, Wqkv_bt, QKV, nullptr, 16384, 2304, 768);
  k_lnrope<<<3072, 256, 0, stream>>>(QKV, cosT, sinT, q_ln_w, q_ln_b, k_ln_w, k_ln_b, Qb, Kb, Vt);
  k_attn<<<1536, 512, 0, stream>>>(Qb, Kb, Vt, O);
  k_gemm<1><<<dim3(128, 6), 256, 0, stream>>>(O, Wproj_bt, d_out, b_proj, 16384, 768, 768);
}

// Round 9
// 354.539 us; speedup vs baseline: 1.0265x; 1.0265x over previous
//
#include <hip/hip_runtime.h>
#include <hip/hip_bf16.h>

// Problem constants: B=16, N=1024, C=768, H=12, D=64, P=1, L=32 (rope tokens [1,992))
typedef __attribute__((ext_vector_type(8))) short v8s;
typedef __attribute__((ext_vector_type(4))) short v4s;
typedef __attribute__((ext_vector_type(4))) float f32x4;

__device__ __forceinline__ float bf2f(short s){
  unsigned u = ((unsigned)(unsigned short)s) << 16;
  float f; __builtin_memcpy(&f, &u, 4); return f;
}
__device__ __forceinline__ short f2bf(float f){
  unsigned u; __builtin_memcpy(&u, &f, 4);
  unsigned r = (u + 0x7FFFu + ((u >> 16) & 1u)) >> 16;
  return (short)r;
}
// packed RNE f32x2 -> bf16x2 (low = a, high = b); no builtin on gfx950 (m240)
__device__ __forceinline__ unsigned cvtpk(float a, float b){
  unsigned r;
  asm("v_cvt_pk_bf16_f32 %0, %1, %2" : "=v"(r) : "v"(a), "v"(b));
  return r;
}

// async global->LDS DMA, 16B per lane; LDS dest = wave-uniform base + lane*16 (m104)
__device__ __forceinline__ void gload16(const void* g, void* l){
  __builtin_amdgcn_global_load_lds((const __attribute__((address_space(1))) void*)g,
                                   (__attribute__((address_space(3))) void*)l, 16, 0, 0);
}

// ---------------- cast fp32 -> bf16 (8 elems/thread) ----------------
__global__ __launch_bounds__(256) void k_cast8(const float* __restrict__ in,
                                               short* __restrict__ out, long n){
  long i = ((long)blockIdx.x * 256 + threadIdx.x) * 8;
  long stride = (long)gridDim.x * 256 * 8;
  for (; i < n; i += stride){
    float4 a = *(const float4*)(in + i);
    float4 b = *(const float4*)(in + i + 4);
    v8s v;
    v[0]=f2bf(a.x); v[1]=f2bf(a.y); v[2]=f2bf(a.z); v[3]=f2bf(a.w);
    v[4]=f2bf(b.x); v[5]=f2bf(b.y); v[6]=f2bf(b.z); v[7]=f2bf(b.w);
    *(v8s*)(out + i) = v;
  }
}

// ------------- transpose+cast: in[R][Cc] f32 -> out[Cc][R] bf16 -------------
__global__ __launch_bounds__(256) void k_tcast(const float* __restrict__ in,
                                               short* __restrict__ out, int R, int Cc){
  __shared__ float T[32][33];
  int tx = threadIdx.x & 31, ty = threadIdx.x >> 5;
  int r0 = blockIdx.x * 32, c0 = blockIdx.y * 32;
  #pragma unroll
  for (int p = 0; p < 4; p++){
    int r = ty + p*8;
    T[r][tx] = in[(long)(r0 + r)*Cc + c0 + tx];
  }
  __syncthreads();
  #pragma unroll
  for (int p = 0; p < 4; p++){
    int r = ty + p*8;
    out[(long)(c0 + r)*R + r0 + tx] = f2bf(T[tx][r]);
  }
}

// ---------------- bf16 GEMM: C[M][N] = A[M][K]*B[K][N], Bt is [N][K] ----------------
// BM=BN=128 BK=64, 256 threads (4 waves). global_load_lds staging into linear LDS
// with involutive swizzle (colbyte ^= (row&7)<<4) applied to SOURCE addr and READ addr.
template<int OUT_MODE>  // 0: bf16 out, 1: f32 out + bias
__global__ __launch_bounds__(256) void k_gemm(const short* __restrict__ A,
                                              const short* __restrict__ Bt,
                                              void* __restrict__ Cout,
                                              const float* __restrict__ bias,
                                              int M, int N, int K){
  __shared__ short As[128*64];
  __shared__ short Bs[128*64];
  int row0 = blockIdx.x * 128, col0 = blockIdx.y * 128;
  int t = threadIdx.x;
  int lane = t & 63, w = t >> 6;
  int g = lane >> 4, r16 = lane & 15;
  int wr = w >> 1, wc = w & 1;
  int rsw = (r16 & 7) << 3;             // read-side swizzle (shorts)
  int srow = t >> 3;                    // staging row within 32-row shot
  int scol = ((t & 7) * 8) ^ ((srow & 7) << 3);  // pre-swizzled source col (shorts)
  f32x4 acc[4][4];
  #pragma unroll
  for (int mi = 0; mi < 4; mi++)
    #pragma unroll
    for (int ni = 0; ni < 4; ni++)
      acc[mi][ni] = (f32x4){0.f,0.f,0.f,0.f};

  for (int kt = 0; kt < K; kt += 64){
    #pragma unroll
    for (int p = 0; p < 4; p++){
      int rr = p*32 + srow;
      gload16(&A[(long)(row0 + rr)*K + kt + scol], &As[(p*256 + w*64)*8]);
    }
    #pragma unroll
    for (int p = 0; p < 4; p++){
      int rr = p*32 + srow;
      gload16(&Bt[(long)(col0 + rr)*K + kt + scol], &Bs[(p*256 + w*64)*8]);
    }
    __syncthreads();
    #pragma unroll
    for (int ks = 0; ks < 2; ks++){
      v8s af[4], bfr[4];
      #pragma unroll
      for (int mi = 0; mi < 4; mi++)
        af[mi] = *(const v8s*)&As[(wr*64 + mi*16 + r16)*64 + ((ks*32 + g*8) ^ rsw)];
      #pragma unroll
      for (int ni = 0; ni < 4; ni++)
        bfr[ni] = *(const v8s*)&Bs[(wc*64 + ni*16 + r16)*64 + ((ks*32 + g*8) ^ rsw)];
      __builtin_amdgcn_s_setprio(1);
      #pragma unroll
      for (int mi = 0; mi < 4; mi++)
        #pragma unroll
        for (int ni = 0; ni < 4; ni++)
          acc[mi][ni] = __builtin_amdgcn_mfma_f32_16x16x32_bf16(af[mi], bfr[ni], acc[mi][ni], 0, 0, 0);
      __builtin_amdgcn_s_setprio(0);
    }
    __syncthreads();
  }
  #pragma unroll
  for (int mi = 0; mi < 4; mi++)
    #pragma unroll
    for (int ni = 0; ni < 4; ni++){
      int rbase = row0 + wr*64 + mi*16 + g*4;
      int cc = col0 + wc*64 + ni*16 + r16;
      #pragma unroll
      for (int j = 0; j < 4; j++){
        float v = acc[mi][ni][j];
        if (OUT_MODE == 0)
          ((short*)Cout)[(long)(rbase + j)*N + cc] = f2bf(v);
        else
          ((float*)Cout)[(long)(rbase + j)*N + cc] = v + bias[cc];
      }
    }
}

// ---------------- LN (over D=64) + RoPE + layout: QKV bf16 -> Qb, Kb (b,h,n,d), Vt (b,h,d,n) ----------------
// Q additionally scaled by D^-0.5 * log2(e) so attention can use exp2 directly.
__global__ __launch_bounds__(256) void k_lnrope(const short* __restrict__ QKV,
     const float* __restrict__ cosT, const float* __restrict__ sinT,
     const float* __restrict__ qw, const float* __restrict__ qb,
     const float* __restrict__ kw, const float* __restrict__ kb,
     short* __restrict__ Qb, short* __restrict__ Kb, short* __restrict__ Vt){
  __shared__ short Vs[64][72];
  int blk = blockIdx.x;
  int ntile = blk & 15, h = (blk >> 4) % 12, b = blk / 192;
  int t = threadIdx.x;
  int tl = t >> 2, ch = t & 3;
  int n = ntile*64 + tl;
  long row = (long)(b*1024 + n) * 2304;
  int d0 = ch * 16;
  long outrow = ((long)(b*12 + h)*1024 + n) * 64;

  #pragma unroll
  for (int sel = 0; sel < 2; sel++){
    const short* src = &QKV[row + sel*768 + h*64 + d0];
    float f[16];
    v8s a0 = *(const v8s*)src;
    v8s a1 = *(const v8s*)(src + 8);
    #pragma unroll
    for (int i = 0; i < 8; i++){ f[i] = bf2f(a0[i]); f[8+i] = bf2f(a1[i]); }
    float s1 = 0.f, s2 = 0.f;
    #pragma unroll
    for (int i = 0; i < 16; i++){ s1 += f[i]; s2 += f[i]*f[i]; }
    s1 += __shfl_xor(s1, 1); s2 += __shfl_xor(s2, 1);
    s1 += __shfl_xor(s1, 2); s2 += __shfl_xor(s2, 2);
    float mu = s1 * (1.0f/64.0f);
    float var = s2 * (1.0f/64.0f) - mu*mu;
    float rs = rsqrtf(var + 1e-5f);
    const float* wp = sel ? kw : qw;
    const float* bp = sel ? kb : qb;
    #pragma unroll
    for (int i = 0; i < 16; i++) f[i] = (f[i] - mu)*rs*wp[d0+i] + bp[d0+i];
    if (n >= 1 && n < 992){
      int pos = n - 1;
      const float* cp = &cosT[pos*32 + ch*8];
      const float* sp = &sinT[pos*32 + ch*8];
      #pragma unroll
      for (int i = 0; i < 8; i++){
        float c = cp[i], s = sp[i];
        float tr = f[2*i], ti = f[2*i+1];
        f[2*i]   = tr*c - ti*s;
        f[2*i+1] = tr*s + ti*c;
      }
    }
    if (sel == 0){
      #pragma unroll
      for (int i = 0; i < 16; i++) f[i] *= 0.18033688011112042f;  // D^-0.5 * log2(e)
    }
    v8s o0, o1;
    #pragma unroll
    for (int i = 0; i < 8; i++){ o0[i] = f2bf(f[i]); o1[i] = f2bf(f[8+i]); }
    short* dst = sel ? &Kb[outrow + d0] : &Qb[outrow + d0];
    *(v8s*)dst = o0;
    *(v8s*)(dst + 8) = o1;
  }
  // V: copy + transpose via LDS
  {
    const short* vsrc = &QKV[row + 1536 + h*64 + d0];
    *(v8s*)&Vs[tl][d0]     = *(const v8s*)vsrc;
    *(v8s*)&Vs[tl][d0 + 8] = *(const v8s*)(vsrc + 8);
  }
  __syncthreads();
  {
    int d = tl, nch = ch;
    v8s o0, o1;
    #pragma unroll
    for (int i = 0; i < 8; i++){ o0[i] = Vs[nch*16 + i][d]; o1[i] = Vs[nch*16 + 8 + i][d]; }
    long vrow = ((long)(b*12 + h)*64 + d)*1024 + ntile*64 + nch*16;
    *(v8s*)&Vt[vrow]     = o0;
    *(v8s*)&Vt[vrow + 8] = o1;
  }
}

// ---------------- flash attention: block = (b,h,qtile=128), 512 threads (8 waves) ----------------
// Wave owns 16 q rows. S^T = K*Q^T so sacc C-regs hold P for q=r16, k=16f+4g+j.
// PV: full-K32 MFMAs, key permutation pi shared by A (cvt_pk'd P, lane-local) and B (Vts reads).
// Serial-shfl elimination: common path has ZERO cross-lane ops except __all;
// max-shfls only inside the rare rescale branch; l reduced once after the loop.
__global__ __launch_bounds__(512) void k_attn(const short* __restrict__ Qb,
                                              const short* __restrict__ Kb,
                                              const short* __restrict__ Vt,
                                              short* __restrict__ O){
  __shared__ short Ks[2][64*64];
  __shared__ short Vts[2][64*64];
  int blk = blockIdx.x;
  int qt = blk & 7, h = (blk >> 3) % 12, b = blk / 96;
  long bh = b*12 + h;
  int t = threadIdx.x, lane = t & 63, w = t >> 6;
  int g = lane >> 4, r16 = lane & 15;
  int rsw = (r16 & 7) << 3;
  int q0 = qt*128 + w*16;

  // staging: 512 threads x 16B = 8KB = one 64x64 bf16 tile per shot
  int srow = t >> 3;                                // 0..63
  int scol = ((t & 7) * 8) ^ ((srow & 7) << 3);     // pre-swizzled col (shorts)
  const short* Ksrc = &Kb[(bh*1024 + srow)*64 + scol];
  const short* Vsrc = &Vt[(bh*64 + srow)*1024 + scol];
  int lbase = w*512;                                // wave-uniform LDS dest (shorts)

  // prologue: stage tile 0 into buffer 0
  gload16(Ksrc, &Ks[0][lbase]);
  gload16(Vsrc, &Vts[0][lbase]);

  v8s bq[2];
  #pragma unroll
  for (int tt = 0; tt < 2; tt++)
    bq[tt] = *(const v8s*)&Qb[(bh*1024 + q0 + r16)*64 + tt*32 + g*8];

  f32x4 oacc[4];
  #pragma unroll
  for (int t2 = 0; t2 < 4; t2++) oacc[t2] = (f32x4){0.f,0.f,0.f,0.f};
  float m_run = -1e30f, l_part = 0.f;   // l_part: per-lane partial (16 keys/lane/tile)

  asm volatile("s_waitcnt vmcnt(0)" ::: "memory");
  __builtin_amdgcn_s_barrier();
  asm volatile("" ::: "memory");

  for (int it = 0; it < 16; ++it){
    int cur = it & 1;
    if (it < 15){  // issue next tile's loads early; they overlap this tile's compute
      int kt = (it + 1) * 64;
      gload16(Ksrc + (long)kt*64, &Ks[cur^1][lbase]);
      gload16(Vsrc + kt,          &Vts[cur^1][lbase]);
    }
    const short* KsC  = &Ks[cur][0];
    const short* VtsC = &Vts[cur][0];

    f32x4 sacc[4];
    #pragma unroll
    for (int f = 0; f < 4; f++) sacc[f] = (f32x4){0.f,0.f,0.f,0.f};
    #pragma unroll
    for (int tt = 0; tt < 2; tt++){
      v8s ak[4];
      #pragma unroll
      for (int f = 0; f < 4; f++)
        ak[f] = *(const v8s*)&KsC[(f*16 + r16)*64 + ((tt*32 + g*8) ^ rsw)];
      __builtin_amdgcn_s_setprio(1);
      #pragma unroll
      for (int f = 0; f < 4; f++)
        sacc[f] = __builtin_amdgcn_mfma_f32_16x16x32_bf16(ak[f], bq[tt], sacc[f], 0, 0, 0);
      __builtin_amdgcn_s_setprio(0);
    }
    // within-lane max only (no cross-lane in common path); lane holds q = r16
    float mf[4];
    #pragma unroll
    for (int f = 0; f < 4; f++)
      mf[f] = fmaxf(fmaxf(sacc[f][0], sacc[f][1]), fmaxf(sacc[f][2], sacc[f][3]));
    float mt_loc = fmaxf(fmaxf(mf[0], mf[1]), fmaxf(mf[2], mf[3]));
    // defer-max (T13): __all IS the cross-lane reduce; shfls only when triggered
    if (!__all(mt_loc - m_run <= 8.0f)){
      float mt = fmaxf(mt_loc, __shfl_xor(mt_loc, 16));
      mt = fmaxf(mt, __shfl_xor(mt, 32));
      float m_new = fmaxf(m_run, mt);
      float alpha = exp2f(m_run - m_new);
      float aj4[4];
      #pragma unroll
      for (int j = 0; j < 4; j++) aj4[j] = __shfl(alpha, 4*g + j, 64);
      #pragma unroll
      for (int t2 = 0; t2 < 4; t2++)
        #pragma unroll
        for (int j = 0; j < 4; j++) oacc[t2][j] *= aj4[j];
      l_part *= alpha;   // per-lane alpha: identical across the 4 lanes of this q
      m_run = m_new;
    }
    float p[4][4];
    float ls[4];
    #pragma unroll
    for (int f = 0; f < 4; f++){
      #pragma unroll
      for (int j = 0; j < 4; j++) p[f][j] = exp2f(sacc[f][j] - m_run);
      ls[f] = (p[f][0] + p[f][1]) + (p[f][2] + p[f][3]);
    }
    l_part += (ls[0] + ls[1]) + (ls[2] + ls[3]);   // no cross-lane reduce here

    // pack P to bf16: D[f] = (pk(p0,p1), pk(p2,p3)); A-frag W[kb] = D[2kb]||D[2kb+1]
    unsigned d00 = cvtpk(p[0][0], p[0][1]), d01 = cvtpk(p[0][2], p[0][3]);
    unsigned d10 = cvtpk(p[1][0], p[1][1]), d11 = cvtpk(p[1][2], p[1][3]);
    unsigned d20 = cvtpk(p[2][0], p[2][1]), d21 = cvtpk(p[2][2], p[2][3]);
    unsigned d30 = cvtpk(p[3][0], p[3][1]), d31 = cvtpk(p[3][2], p[3][3]);
    union PU { v8s s; unsigned u[4]; };
    PU pa0, pa1;
    pa0.u[0]=d00; pa0.u[1]=d01; pa0.u[2]=d10; pa0.u[3]=d11;
    pa1.u[0]=d20; pa1.u[1]=d21; pa1.u[2]=d30; pa1.u[3]=d31;

    // PV: B-frag lane supplies V[pi(kb,8g+i)][d=t2*16+r16] = two 4-elem runs of Vts row
    #pragma unroll
    for (int t2 = 0; t2 < 4; t2++){
      int vrow = (t2*16 + r16)*64;
      #pragma unroll
      for (int kb = 0; kb < 2; kb++){
        union VU { v8s s; v4s h[2]; } vb;
        vb.h[0] = *(const v4s*)&VtsC[vrow + ((kb*32 + g*4) ^ rsw)];
        vb.h[1] = *(const v4s*)&VtsC[vrow + ((kb*32 + 16 + g*4) ^ rsw)];
        __builtin_amdgcn_s_setprio(1);
        oacc[t2] = __builtin_amdgcn_mfma_f32_16x16x32_bf16(kb ? pa1.s : pa0.s, vb.s, oacc[t2], 0, 0, 0);
        __builtin_amdgcn_s_setprio(0);
      }
    }
    // end-of-tile sync: wait next tile's staged loads, then barrier (buffer swap safe)
    asm volatile("s_waitcnt vmcnt(0)" ::: "memory");
    __builtin_amdgcn_s_barrier();
    asm volatile("" ::: "memory");
  }
  // final l reduction (once): sum the 4 per-lane partials of each q
  float l_tot = l_part;
  l_tot += __shfl_xor(l_tot, 16);
  l_tot += __shfl_xor(l_tot, 32);
  float linv = 1.0f / l_tot;
  float lj[4];
  #pragma unroll
  for (int j = 0; j < 4; j++) lj[j] = __shfl(linv, 4*g + j, 64);
  #pragma unroll
  for (int t2 = 0; t2 < 4; t2++)
    #pragma unroll
    for (int j = 0; j < 4; j++){
      float v = oacc[t2][j] * lj[j];
      O[((long)b*1024 + q0 + 4*g + j)*768 + h*64 + t2*16 + r16] = f2bf(v);
    }
}

extern "C" void kernel_launch(void* const* d_in, const int* in_sizes, int n_in,
                              void* d_out, int out_size, void* d_ws, size_t ws_size,
                              hipStream_t stream) {
  const float* x      = (const float*)d_in[0];
  const float* cosT   = (const float*)d_in[1];
  const float* sinT   = (const float*)d_in[2];
  const float* w_qkv  = (const float*)d_in[3];
  const float* q_ln_w = (const float*)d_in[4];
  const float* q_ln_b = (const float*)d_in[5];
  const float* k_ln_w = (const float*)d_in[6];
  const float* k_ln_b = (const float*)d_in[7];
  const float* w_proj = (const float*)d_in[8];
  const float* b_proj = (const float*)d_in[9];

  char* ws = (char*)d_ws;
  short* Xb       = (short*)(ws);                    // 16384x768   bf16: 25165824 B
  short* Wqkv_bt  = (short*)(ws + 25165824);         // 2304x768    bf16:  3538944 B
  short* Wproj_bt = (short*)(ws + 28704768);         // 768x768     bf16:  1179648 B
  short* QKV      = (short*)(ws + 29884416);         // 16384x2304  bf16: 75497472 B
  short* Qb       = (short*)(ws + 105381888);        // (b,h,n,d)   bf16: 25165824 B
  short* Kb       = (short*)(ws + 130547712);        // (b,h,n,d)   bf16: 25165824 B
  short* Vt       = (short*)(ws + 155713536);        // (b,h,d,n)   bf16: 25165824 B
  short* O        = (short*)(ws + 180879360);        // 16384x768   bf16: 25165824 B
  // total 206045184 B

  k_cast8<<<6144, 256, 0, stream>>>(x, Xb, 12582912L);
  k_tcast<<<dim3(24, 72), 256, 0, stream>>>(w_qkv, Wqkv_bt, 768, 2304);
  k_tcast<<<dim3(24, 24), 256, 0, stream>>>(w_proj, Wproj_bt, 768, 768);
  k_gemm<0><<<dim3(128, 18), 256, 0, stream>>>(Xb, Wqkv_bt, QKV, nullptr, 16384, 2304, 768);
  k_lnrope<<<3072, 256, 0, stream>>>(QKV, cosT, sinT, q_ln_w, q_ln_b, k_ln_w, k_ln_b, Qb, Kb, Vt);
  k_attn<<<1536, 512, 0, stream>>>(Qb, Kb, Vt, O);
  k_gemm<1><<<dim3(128, 6), 256, 0, stream>>>(O, Wproj_bt, d_out, b_proj, 16384, 768, 768);
}